// Round 2
// baseline (415.644 us; speedup 1.0000x reference)
//
#include <hip/hip_runtime.h>
#include <hip/hip_bf16.h>

// out[i, r, c] = dot(q[i, r, :], e[h, L-1-(r-c), :])  for c <= r, else 0
// (fp32 in, fp32 out). GEMM T[r, k] = q[r,:] . e_rev[k,:]  (k = r - c).
// Block (x=r-tile, y=k-tile): y<=x -> MFMA compute (fp32 loaded, cast to bf16
// fragments in-register, fp32 accum) + skewed fp32 write (c = r-k >= 0);
// y>=x -> zero-fill cells with c > r in out-tile (x,y).
// Every output element written exactly once.

typedef __bf16 bf16x8 __attribute__((ext_vector_type(8)));
typedef float  f32x4  __attribute__((ext_vector_type(4)));
typedef float  f32x8  __attribute__((ext_vector_type(8)));

constexpr int L = 2048;
constexpr int D = 64;

__device__ __forceinline__ bf16x8 load_cvt8(const float* __restrict__ p) {
  f32x8 v = *(const f32x8*)p;       // 2x global_load_dwordx4
  bf16x8 r;
#pragma unroll
  for (int j = 0; j < 8; ++j) r[j] = (__bf16)v[j];
  return r;
}

__global__ __launch_bounds__(256) void skew_mfma(const float* __restrict__ q,
                                                 const float* __restrict__ e,
                                                 float* __restrict__ out) {
  const int tid  = threadIdx.x;
  const int lane = tid & 63;
  const int w    = tid >> 6;        // wave 0..3 -> n-strip of 16 diagonals
  const int ln   = lane & 15;
  const int quad = lane >> 4;
  const int y = blockIdx.x;         // k-tile (compute) / c-tile (zero)
  const int x = blockIdx.y;         // r-tile
  const int i = blockIdx.z;         // bh index, h = i & 7
  const int h = i & 7;
  const int r0 = x << 6;
  const int z0 = y << 6;            // k0 (compute) or c0 (zero)

  float* obase = out + (size_t)i * L * L;

  if (y <= x) {
    // ---- MFMA compute: T[r, n] = sum_d q[i,r,d] * e[h, L-1-n, d] ----
    const int n    = z0 + (w << 4) + ln;   // global diagonal index (B column)
    const int erow = (L - 1) - n;          // reversed e row
    const float* eptr = e + ((size_t)(h * L + erow)) * D + quad * 8;
    const float* qptr = q + ((size_t)(i * L + r0 + ln)) * D + quad * 8;

    f32x4 acc0 = {0.f, 0.f, 0.f, 0.f};
    f32x4 acc1 = acc0, acc2 = acc0, acc3 = acc0;

#pragma unroll
    for (int kk = 0; kk < D; kk += 32) {
      // B fragment: lane holds B[k=quad*8+j][n=lane&15] = e_rev[n][kk+quad*8+j]
      bf16x8 bf = load_cvt8(eptr + kk);
      // A fragments: lane holds A[m=lane&15][k=quad*8+j] for 4 m-subtiles
      bf16x8 a0 = load_cvt8(qptr + 0 * 16 * D + kk);
      bf16x8 a1 = load_cvt8(qptr + 1 * 16 * D + kk);
      bf16x8 a2 = load_cvt8(qptr + 2 * 16 * D + kk);
      bf16x8 a3 = load_cvt8(qptr + 3 * 16 * D + kk);
      acc0 = __builtin_amdgcn_mfma_f32_16x16x32_bf16(a0, bf, acc0, 0, 0, 0);
      acc1 = __builtin_amdgcn_mfma_f32_16x16x32_bf16(a1, bf, acc1, 0, 0, 0);
      acc2 = __builtin_amdgcn_mfma_f32_16x16x32_bf16(a2, bf, acc2, 0, 0, 0);
      acc3 = __builtin_amdgcn_mfma_f32_16x16x32_bf16(a3, bf, acc3, 0, 0, 0);
    }

    // Epilogue: D row=(lane>>4)*4+reg, col=lane&15 ; out c = r - n, keep c >= 0
#pragma unroll
    for (int mi = 0; mi < 4; mi++) {
      f32x4 a = (mi == 0) ? acc0 : (mi == 1) ? acc1 : (mi == 2) ? acc2 : acc3;
#pragma unroll
      for (int reg = 0; reg < 4; reg++) {
        const int r = r0 + mi * 16 + quad * 4 + reg;
        const int c = r - n;
        if (c >= 0) obase[(size_t)r * L + c] = a[reg];
      }
    }
  }

  if (y >= x) {
    // ---- zero-fill: cells with c > r in out-tile (x, y) ----
    if (y > x) {
      // whole 64x64 fp32 tile strictly-upper: 64 rows x 256 B = 1024 uint4
      uint4 zz = make_uint4(0u, 0u, 0u, 0u);
#pragma unroll
      for (int it = 0; it < 4; it++) {
        const int idx = it * 256 + tid;       // 0..1023
        const int rr  = idx >> 4;
        const int j   = idx & 15;
        *(uint4*)(obase + (size_t)(r0 + rr) * L + z0 + j * 4) = zz;
      }
    } else {
      // diagonal tile (y == x): zero cc > rr only (ragged, small volume)
      const int rr = tid >> 2, s = tid & 3;
      float* rowp = obase + (size_t)(r0 + rr) * L + z0;
      for (int cc = rr + 1 + s; cc < 64; cc += 4) rowp[cc] = 0.f;
    }
  }
}

extern "C" void kernel_launch(void* const* d_in, const int* in_sizes, int n_in,
                              void* d_out, int out_size, void* d_ws, size_t ws_size,
                              hipStream_t stream) {
  const float* q = (const float*)d_in[0];   // (2, 8, 2048, 64) fp32
  const float* e = (const float*)d_in[1];   // (8, 2048, 64) fp32
  float* out = (float*)d_out;               // (2, 8, 2048, 2048) fp32

  dim3 grid(32, 32, 16);   // (k/c-tile, r-tile, bh)
  skew_mfma<<<grid, 256, 0, stream>>>(q, e, out);
}

// Round 4
// 407.887 us; speedup vs baseline: 1.0190x; 1.0190x over previous
//
#include <hip/hip_runtime.h>
#include <hip/hip_bf16.h>

// out[i, r, c] = dot(q[i, r, :], e[h, L-1-(r-c), :])  for c <= r, else 0
// (fp32 in, fp32 out). GEMM T[r, k] = q[r,:] . e_rev[k,:]  (k = r - c).
// Block (x=r-tile, y=k-tile): y<=x -> MFMA compute (fp32 loads, in-register
// bf16 cast, fp32 accum), tile staged via LDS so each output row is stored
// as ONE contiguous 256 B wave-store over cols [r-z0-63, r-z0]; note the
// skew REVERSES columns: c = r-z0-63+lane  <=>  tile col nn = 63-lane.
// y>=x -> zero-fill cells with c > r in out-tile (x,y).
// Every output element written exactly once.

typedef __bf16 bf16x8 __attribute__((ext_vector_type(8)));
typedef float  f32x4  __attribute__((ext_vector_type(4)));
typedef float  f32x8  __attribute__((ext_vector_type(8)));

constexpr int L = 2048;
constexpr int D = 64;
constexpr int LDP = 68;   // LDS row stride (pad 4 dwords): 2-way conflicts only (free)

__device__ __forceinline__ bf16x8 load_cvt8(const float* __restrict__ p) {
  f32x8 v = *(const f32x8*)p;       // 2x global_load_dwordx4
  bf16x8 r;
#pragma unroll
  for (int j = 0; j < 8; ++j) r[j] = (__bf16)v[j];
  return r;
}

__global__ __launch_bounds__(256) void skew_mfma(const float* __restrict__ q,
                                                 const float* __restrict__ e,
                                                 float* __restrict__ out) {
  const int tid  = threadIdx.x;
  const int lane = tid & 63;
  const int w    = tid >> 6;        // wave 0..3 -> n-strip of 16 diagonals
  const int ln   = lane & 15;
  const int quad = lane >> 4;
  const int y = blockIdx.x;         // k-tile (compute) / c-tile (zero)
  const int x = blockIdx.y;         // r-tile
  const int i = blockIdx.z;         // bh index, h = i & 7
  const int h = i & 7;
  const int r0 = x << 6;
  const int z0 = y << 6;            // k0 (compute) or c0 (zero)

  __shared__ float tile[64][LDP];

  float* obase = out + (size_t)i * L * L;

  if (y <= x) {
    // ---- MFMA compute: T[r, n] = sum_d q[i,r,d] * e[h, L-1-n, d] ----
    const int n    = z0 + (w << 4) + ln;   // global diagonal index (B column)
    const int erow = (L - 1) - n;          // reversed e row
    const float* eptr = e + ((size_t)(h * L + erow)) * D + quad * 8;
    const float* qptr = q + ((size_t)(i * L + r0 + ln)) * D + quad * 8;

    f32x4 acc0 = {0.f, 0.f, 0.f, 0.f};
    f32x4 acc1 = acc0, acc2 = acc0, acc3 = acc0;

#pragma unroll
    for (int kk = 0; kk < D; kk += 32) {
      // B fragment: lane holds B[k=quad*8+j][n=lane&15] = e_rev[n][kk+quad*8+j]
      bf16x8 bf = load_cvt8(eptr + kk);
      // A fragments: lane holds A[m=lane&15][k=quad*8+j] for 4 m-subtiles
      bf16x8 a0 = load_cvt8(qptr + 0 * 16 * D + kk);
      bf16x8 a1 = load_cvt8(qptr + 1 * 16 * D + kk);
      bf16x8 a2 = load_cvt8(qptr + 2 * 16 * D + kk);
      bf16x8 a3 = load_cvt8(qptr + 3 * 16 * D + kk);
      acc0 = __builtin_amdgcn_mfma_f32_16x16x32_bf16(a0, bf, acc0, 0, 0, 0);
      acc1 = __builtin_amdgcn_mfma_f32_16x16x32_bf16(a1, bf, acc1, 0, 0, 0);
      acc2 = __builtin_amdgcn_mfma_f32_16x16x32_bf16(a2, bf, acc2, 0, 0, 0);
      acc3 = __builtin_amdgcn_mfma_f32_16x16x32_bf16(a3, bf, acc3, 0, 0, 0);
    }

    // Stage tile in LDS: C-layout row = mi*16 + quad*4 + reg, col = w*16 + ln
#pragma unroll
    for (int mi = 0; mi < 4; mi++) {
      f32x4 a = (mi == 0) ? acc0 : (mi == 1) ? acc1 : (mi == 2) ? acc2 : acc3;
#pragma unroll
      for (int reg = 0; reg < 4; reg++)
        tile[mi * 16 + quad * 4 + reg][(w << 4) + ln] = a[reg];
    }
    __syncthreads();

    // Row-contiguous stores: row r spans cols [r-z0-63, r-z0] (64 dwords).
    // c = r - n  =>  tile column nn = r - c - z0 = 63 - lane (skew reversal).
    // Waves interleave rows (rr = it*4 + w); lane = col offset within span.
#pragma unroll
    for (int it = 0; it < 16; ++it) {
      const int rr = (it << 2) + w;
      const int r  = r0 + rr;
      const int c  = r - z0 - 63 + lane;   // >= 1 whenever y < x
      const float v = tile[rr][63 - lane];
      if (c >= 0) obase[(size_t)r * L + c] = v;
    }
  }

  if (y >= x) {
    // ---- zero-fill: cells with c > r in out-tile (x, y) ----
    if (y > x) {
      // whole 64x64 fp32 tile strictly-upper: 64 rows x 256 B = 1024 uint4
      uint4 zz = make_uint4(0u, 0u, 0u, 0u);
#pragma unroll
      for (int it = 0; it < 4; it++) {
        const int idx = it * 256 + tid;       // 0..1023
        const int rr  = idx >> 4;
        const int j   = idx & 15;
        *(uint4*)(obase + (size_t)(r0 + rr) * L + z0 + j * 4) = zz;
      }
    } else {
      // diagonal out-tile (x,x): zero cc > rr only (ragged, small volume)
      const int rr = tid >> 2, s = tid & 3;
      float* rowp = obase + (size_t)(r0 + rr) * L + z0;
      for (int cc = rr + 1 + s; cc < 64; cc += 4) rowp[cc] = 0.f;
    }
  }
}

extern "C" void kernel_launch(void* const* d_in, const int* in_sizes, int n_in,
                              void* d_out, int out_size, void* d_ws, size_t ws_size,
                              hipStream_t stream) {
  const float* q = (const float*)d_in[0];   // (2, 8, 2048, 64) fp32
  const float* e = (const float*)d_in[1];   // (8, 2048, 64) fp32
  float* out = (float*)d_out;               // (2, 8, 2048, 2048) fp32

  dim3 grid(32, 32, 16);   // (k/c-tile, r-tile, bh)
  skew_mfma<<<grid, 256, 0, stream>>>(q, e, out);
}

// Round 5
// 345.346 us; speedup vs baseline: 1.2036x; 1.1811x over previous
//
#include <hip/hip_runtime.h>
#include <hip/hip_bf16.h>

// out[i, r, c] = dot(q[i, r, :], e[h, L-1-(r-c), :])  for c <= r, else 0
// (fp32 in, fp32 out). GEMM T[r, k] = q[r,:] . e_rev[k,:]  (k = r - c).
// Block (x=r-tile, y=k-tile): y<=x -> MFMA compute (fp32 loads, in-register
// bf16 cast, fp32 accum), tile staged via LDS so each output row is stored
// as ONE contiguous 256 B wave-store over cols [r-z0-63, r-z0]; the skew
// REVERSES columns: c = r-z0-63+lane  <=>  tile col nn = 63-lane.
// y>=x -> zero-fill cells with c > r in out-tile (x,y).
// Grid is (i, x, y) with y SLOWEST so consecutive y-tiles of one (i,x) row
// strip differ by 512 in dispatch id == 0 mod 8 -> same XCD -> the 128 B
// lines split between adjacent column tiles merge in one L2 (full-line
// writebacks instead of cross-XCD partial sectors).
// Every output element written exactly once.

typedef __bf16 bf16x8 __attribute__((ext_vector_type(8)));
typedef float  f32x4  __attribute__((ext_vector_type(4)));
typedef float  f32x8  __attribute__((ext_vector_type(8)));

constexpr int L = 2048;
constexpr int D = 64;
constexpr int LDP = 68;   // LDS row stride (pad 4 dwords): 2-way conflicts only (free)

__device__ __forceinline__ bf16x8 load_cvt8(const float* __restrict__ p) {
  f32x8 v = *(const f32x8*)p;       // 2x global_load_dwordx4
  bf16x8 r;
#pragma unroll
  for (int j = 0; j < 8; ++j) r[j] = (__bf16)v[j];
  return r;
}

__global__ __launch_bounds__(256) void skew_mfma(const float* __restrict__ q,
                                                 const float* __restrict__ e,
                                                 float* __restrict__ out) {
  const int tid  = threadIdx.x;
  const int lane = tid & 63;
  const int w    = tid >> 6;        // wave 0..3
  const int ln   = lane & 15;
  const int quad = lane >> 4;
  const int i = blockIdx.x;         // bh index (fastest), h = i & 7
  const int x = blockIdx.y;         // r-tile
  const int y = blockIdx.z;         // k-tile (compute) / c-tile (zero), SLOWEST
  const int h = i & 7;
  const int r0 = x << 6;
  const int z0 = y << 6;            // k0 (compute) or c0 (zero)

  __shared__ float tile[64][LDP];

  float* obase = out + (size_t)i * L * L;

  if (y <= x) {
    // ---- MFMA compute: T[r, n] = sum_d q[i,r,d] * e[h, L-1-n, d] ----
    const int n    = z0 + (w << 4) + ln;   // global diagonal index (B column)
    const int erow = (L - 1) - n;          // reversed e row
    const float* eptr = e + ((size_t)(h * L + erow)) * D + quad * 8;
    const float* qptr = q + ((size_t)(i * L + r0 + ln)) * D + quad * 8;

    f32x4 acc0 = {0.f, 0.f, 0.f, 0.f};
    f32x4 acc1 = acc0, acc2 = acc0, acc3 = acc0;

#pragma unroll
    for (int kk = 0; kk < D; kk += 32) {
      // B fragment: lane holds B[k=quad*8+j][n=lane&15] = e_rev[n][kk+quad*8+j]
      bf16x8 bf = load_cvt8(eptr + kk);
      // A fragments: lane holds A[m=lane&15][k=quad*8+j] for 4 m-subtiles
      bf16x8 a0 = load_cvt8(qptr + 0 * 16 * D + kk);
      bf16x8 a1 = load_cvt8(qptr + 1 * 16 * D + kk);
      bf16x8 a2 = load_cvt8(qptr + 2 * 16 * D + kk);
      bf16x8 a3 = load_cvt8(qptr + 3 * 16 * D + kk);
      acc0 = __builtin_amdgcn_mfma_f32_16x16x32_bf16(a0, bf, acc0, 0, 0, 0);
      acc1 = __builtin_amdgcn_mfma_f32_16x16x32_bf16(a1, bf, acc1, 0, 0, 0);
      acc2 = __builtin_amdgcn_mfma_f32_16x16x32_bf16(a2, bf, acc2, 0, 0, 0);
      acc3 = __builtin_amdgcn_mfma_f32_16x16x32_bf16(a3, bf, acc3, 0, 0, 0);
    }

    // Stage tile in LDS: C-layout row = mi*16 + quad*4 + reg, col = w*16 + ln
#pragma unroll
    for (int mi = 0; mi < 4; mi++) {
      f32x4 a = (mi == 0) ? acc0 : (mi == 1) ? acc1 : (mi == 2) ? acc2 : acc3;
#pragma unroll
      for (int reg = 0; reg < 4; reg++)
        tile[mi * 16 + quad * 4 + reg][(w << 4) + ln] = a[reg];
    }
    __syncthreads();

    // Row-contiguous stores: row r spans cols [r-z0-63, r-z0] (64 dwords).
    // c = r - n  =>  tile column nn = r - c - z0 = 63 - lane (skew reversal).
#pragma unroll
    for (int it = 0; it < 16; ++it) {
      const int rr = (it << 2) + w;
      const int r  = r0 + rr;
      const int c  = r - z0 - 63 + lane;   // >= 1 whenever y < x
      const float v = tile[rr][63 - lane];
      if (c >= 0) obase[(size_t)r * L + c] = v;
    }
  }

  if (y >= x) {
    // ---- zero-fill: cells with c > r in out-tile (x, y) ----
    if (y > x) {
      // whole 64x64 fp32 tile strictly-upper: 64 rows x 256 B = 1024 uint4
      uint4 zz = make_uint4(0u, 0u, 0u, 0u);
#pragma unroll
      for (int it = 0; it < 4; it++) {
        const int idx = it * 256 + tid;       // 0..1023
        const int rr  = idx >> 4;
        const int j   = idx & 15;
        *(uint4*)(obase + (size_t)(r0 + rr) * L + z0 + j * 4) = zz;
      }
    } else {
      // diagonal out-tile (x,x): zero cc in [rr+1, 63] — one contiguous
      // wave-store per row (waves interleave rows)
#pragma unroll
      for (int it = 0; it < 16; ++it) {
        const int rr = (it << 2) + w;
        const int cc = rr + 1 + lane;
        if (cc < 64) obase[(size_t)(r0 + rr) * L + z0 + cc] = 0.f;
      }
    }
  }
}

extern "C" void kernel_launch(void* const* d_in, const int* in_sizes, int n_in,
                              void* d_out, int out_size, void* d_ws, size_t ws_size,
                              hipStream_t stream) {
  const float* q = (const float*)d_in[0];   // (2, 8, 2048, 64) fp32
  const float* e = (const float*)d_in[1];   // (8, 2048, 64) fp32
  float* out = (float*)d_out;               // (2, 8, 2048, 2048) fp32

  dim3 grid(16, 32, 32);   // (bh, r-tile, c/k-tile) — y slowest: same-XCD row strips
  skew_mfma<<<grid, 256, 0, stream>>>(q, e, out);
}

// Round 6
// 325.918 us; speedup vs baseline: 1.2753x; 1.0596x over previous
//
#include <hip/hip_runtime.h>
#include <hip/hip_bf16.h>

// out[i, r, c] = dot(q[i, r, :], e[h, L-1-(r-c), :])  for c <= r, else 0
// (fp32 in, fp32 out).  T[r, n] = q[r,:] . e_rev[n,:]  (n = r - c).
// Block (i, x, j): OUTPUT tile rows [64x, 64x+64) x cols [64j, 64j+64).
//   j <= x : needed diagonals n = r-c span [base-63, base+63], base = 64(x-j)
//            -> compute a 64x128 T-strip (two 64-wide k-tiles) with MFMA
//            (fp32 loads, in-register bf16 cast, fp32 accum), stage in LDS,
//            then store each output row's ALIGNED 256 B segment as one
//            wave-store (2 full 128 B lines, no partial lines, no masking;
//            diagonal tile j==x selects 0 for c > r via cndmask).
//   j > x  : aligned uint4 zero-fill of the whole tile.
// Every output element written exactly once; all global stores 256 B aligned.

typedef __bf16 bf16x8 __attribute__((ext_vector_type(8)));
typedef float  f32x4  __attribute__((ext_vector_type(4)));
typedef float  f32x8  __attribute__((ext_vector_type(8)));

constexpr int L = 2048;
constexpr int D = 64;
constexpr int LDP = 132;   // LDS row stride (128 + 4 pad)

__device__ __forceinline__ bf16x8 load_cvt8(const float* __restrict__ p) {
  f32x8 v = *(const f32x8*)p;       // 2x global_load_dwordx4
  bf16x8 r;
#pragma unroll
  for (int j = 0; j < 8; ++j) r[j] = (__bf16)v[j];
  return r;
}

__global__ __launch_bounds__(256) void skew_mfma(const float* __restrict__ q,
                                                 const float* __restrict__ e,
                                                 float* __restrict__ out) {
  const int tid  = threadIdx.x;
  const int lane = tid & 63;
  const int w    = tid >> 6;        // wave 0..3
  const int ln   = lane & 15;
  const int quad = lane >> 4;
  const int i = blockIdx.x;         // bh index (fastest), h = i & 7
  const int x = blockIdx.y;         // r-tile
  const int j = blockIdx.z;         // c-tile (slowest)
  const int h = i & 7;
  const int r0 = x << 6;
  const int c0 = j << 6;

  __shared__ float tile[64][LDP];

  float* obase = out + (size_t)i * L * L;

  if (j <= x) {
    const int base = (x - j) << 6;        // r0 - c0
    const int diag = (j == x);            // block-uniform

    // A fragments: lane holds A[m=ln][k=quad*8+jj] for 4 m-subtiles
    const float* qptr = q + ((size_t)(i * L + r0 + ln)) * D + quad * 8;

    f32x4 acc[2][4];
#pragma unroll
    for (int nb = 0; nb < 2; nb++)
#pragma unroll
      for (int mi = 0; mi < 4; mi++) acc[nb][mi] = (f32x4){0.f, 0.f, 0.f, 0.f};

#pragma unroll
    for (int kk = 0; kk < D; kk += 32) {
      bf16x8 a0 = load_cvt8(qptr + 0 * 16 * D + kk);
      bf16x8 a1 = load_cvt8(qptr + 1 * 16 * D + kk);
      bf16x8 a2 = load_cvt8(qptr + 2 * 16 * D + kk);
      bf16x8 a3 = load_cvt8(qptr + 3 * 16 * D + kk);
#pragma unroll
      for (int nb = 0; nb < 2; nb++) {
        if (diag && nb == 0) continue;    // n < 0: unused, avoid OOB e read
        // B fragment: cols n = base-64+nb*64 + w*16 + ln, k = quad*8+jj
        const int n    = base - 64 + (nb << 6) + (w << 4) + ln;
        const int erow = (L - 1) - n;
        bf16x8 bf = load_cvt8(e + ((size_t)(h * L + erow)) * D + quad * 8 + kk);
        acc[nb][0] = __builtin_amdgcn_mfma_f32_16x16x32_bf16(a0, bf, acc[nb][0], 0, 0, 0);
        acc[nb][1] = __builtin_amdgcn_mfma_f32_16x16x32_bf16(a1, bf, acc[nb][1], 0, 0, 0);
        acc[nb][2] = __builtin_amdgcn_mfma_f32_16x16x32_bf16(a2, bf, acc[nb][2], 0, 0, 0);
        acc[nb][3] = __builtin_amdgcn_mfma_f32_16x16x32_bf16(a3, bf, acc[nb][3], 0, 0, 0);
      }
    }

    // Stage: C-layout row = mi*16 + quad*4 + reg, LDS col nn = n-(base-64)
#pragma unroll
    for (int nb = 0; nb < 2; nb++) {
      if (diag && nb == 0) continue;
#pragma unroll
      for (int mi = 0; mi < 4; mi++)
#pragma unroll
        for (int reg = 0; reg < 4; reg++)
          tile[mi * 16 + quad * 4 + reg][(nb << 6) + (w << 4) + ln] = acc[nb][mi][reg];
    }
    __syncthreads();

    // Aligned stores: row r, cols [c0, c0+64).  c = c0+lane, n = r-c,
    // nn = n-(base-64) = 64 + rr - lane  (in [1,127]); diag: c>r -> 0.
#pragma unroll
    for (int it = 0; it < 16; ++it) {
      const int rr = (it << 2) + w;
      float v = tile[rr][64 + rr - lane];
      if (diag && lane > rr) v = 0.f;
      obase[(size_t)(r0 + rr) * L + c0 + lane] = v;
    }
  } else {
    // ---- j > x: whole 64x64 fp32 tile strictly-upper: zero-fill ----
    uint4 zz = make_uint4(0u, 0u, 0u, 0u);
#pragma unroll
    for (int it = 0; it < 4; it++) {
      const int idx = it * 256 + tid;       // 0..1023
      const int rr  = idx >> 4;
      const int jj  = idx & 15;
      *(uint4*)(obase + (size_t)(r0 + rr) * L + c0 + jj * 4) = zz;
    }
  }
}

extern "C" void kernel_launch(void* const* d_in, const int* in_sizes, int n_in,
                              void* d_out, int out_size, void* d_ws, size_t ws_size,
                              hipStream_t stream) {
  const float* q = (const float*)d_in[0];   // (2, 8, 2048, 64) fp32
  const float* e = (const float*)d_in[1];   // (8, 2048, 64) fp32
  float* out = (float*)d_out;               // (2, 8, 2048, 2048) fp32

  dim3 grid(16, 32, 32);   // (bh, r-tile, c-tile)
  skew_mfma<<<grid, 256, 0, stream>>>(q, e, out);
}

// Round 7
// 325.588 us; speedup vs baseline: 1.2766x; 1.0010x over previous
//
#include <hip/hip_runtime.h>
#include <hip/hip_bf16.h>

// out[i, r, c] = dot(q[i, r, :], e[h, L-1-(r-c), :])  for c <= r, else 0
// (fp32 in, fp32 out).  T[r, n] = q[r,:] . e_rev[n,:]  (n = r - c).
// Block (i, p): p decodes (x, j), j <= x.  The block:
//   1) zero-fills the mirrored strictly-upper tile (31-x, 31-j) when j < x
//      (independent stores — scheduler issues them under MFMA/LDS latency);
//   2) computes output tile rows [64x,..+64) x cols [64j,..+64): diagonals
//      n = r-c span [base-63, base+63], base = 64(x-j) -> 64x128 T-strip via
//      MFMA (fp32 loads, in-register bf16 cast, fp32 accum), staged in LDS,
//      each row stored as one ALIGNED 256 B wave-store (diag masks c>r to 0).
// Every output element written exactly once; all global stores 256 B aligned;
// every block has identical work (no zero-only light blocks -> no tail).

typedef __bf16 bf16x8 __attribute__((ext_vector_type(8)));
typedef float  f32x4  __attribute__((ext_vector_type(4)));
typedef float  f32x8  __attribute__((ext_vector_type(8)));

constexpr int L = 2048;
constexpr int D = 64;
constexpr int NT = 32;     // tiles per side
constexpr int LDP = 132;   // LDS row stride (128 + 4 pad)

__device__ __forceinline__ bf16x8 load_cvt8(const float* __restrict__ p) {
  f32x8 v = *(const f32x8*)p;       // 2x global_load_dwordx4
  bf16x8 r;
#pragma unroll
  for (int j = 0; j < 8; ++j) r[j] = (__bf16)v[j];
  return r;
}

__global__ __launch_bounds__(256) void skew_mfma(const float* __restrict__ q,
                                                 const float* __restrict__ e,
                                                 float* __restrict__ out) {
  const int tid  = threadIdx.x;
  const int lane = tid & 63;
  const int w    = tid >> 6;        // wave 0..3
  const int ln   = lane & 15;
  const int quad = lane >> 4;
  const int i = blockIdx.x;         // bh index (fastest), h = i & 7
  const int p = blockIdx.y;         // lower-triangle pair index, 0..527
  const int h = i & 7;

  // decode p -> (x, j), j <= x (row-major over lower triangle)
  float t = __builtin_sqrtf(8.f * (float)p + 1.f);
  int x = (int)((t - 1.f) * 0.5f);
  if ((x + 1) * (x + 2) / 2 <= p) ++x;
  if (x * (x + 1) / 2 > p) --x;
  const int j  = p - x * (x + 1) / 2;
  const int r0 = x << 6;
  const int c0 = j << 6;
  const int diag = (j == x);        // block-uniform

  __shared__ float tile[64][LDP];

  float* obase = out + (size_t)i * L * L;

  // ---- mirrored strictly-upper tile (NT-1-x, NT-1-j): pure zero-fill ----
  if (!diag) {
    const int r0z = (NT - 1 - x) << 6;
    const int c0z = (NT - 1 - j) << 6;
    uint4 zz = make_uint4(0u, 0u, 0u, 0u);
#pragma unroll
    for (int it = 0; it < 4; it++) {
      const int idx = it * 256 + tid;       // 0..1023
      const int rr  = idx >> 4;
      const int jj  = idx & 15;
      *(uint4*)(obase + (size_t)(r0z + rr) * L + c0z + jj * 4) = zz;
    }
  }

  // ---- compute tile (x, j) ----
  {
    const int base = (x - j) << 6;        // r0 - c0

    // A fragments: lane holds A[m=ln][k=quad*8+jj] for 4 m-subtiles
    const float* qptr = q + ((size_t)(i * L + r0 + ln)) * D + quad * 8;

    f32x4 acc[2][4];
#pragma unroll
    for (int nb = 0; nb < 2; nb++)
#pragma unroll
      for (int mi = 0; mi < 4; mi++) acc[nb][mi] = (f32x4){0.f, 0.f, 0.f, 0.f};

#pragma unroll
    for (int kk = 0; kk < D; kk += 32) {
      bf16x8 a0 = load_cvt8(qptr + 0 * 16 * D + kk);
      bf16x8 a1 = load_cvt8(qptr + 1 * 16 * D + kk);
      bf16x8 a2 = load_cvt8(qptr + 2 * 16 * D + kk);
      bf16x8 a3 = load_cvt8(qptr + 3 * 16 * D + kk);
#pragma unroll
      for (int nb = 0; nb < 2; nb++) {
        if (diag && nb == 0) continue;    // n < 0: unused, avoid OOB e read
        // B fragment: cols n = base-64+nb*64 + w*16 + ln, k = quad*8+jj
        const int n    = base - 64 + (nb << 6) + (w << 4) + ln;
        const int erow = (L - 1) - n;
        bf16x8 bf = load_cvt8(e + ((size_t)(h * L + erow)) * D + quad * 8 + kk);
        acc[nb][0] = __builtin_amdgcn_mfma_f32_16x16x32_bf16(a0, bf, acc[nb][0], 0, 0, 0);
        acc[nb][1] = __builtin_amdgcn_mfma_f32_16x16x32_bf16(a1, bf, acc[nb][1], 0, 0, 0);
        acc[nb][2] = __builtin_amdgcn_mfma_f32_16x16x32_bf16(a2, bf, acc[nb][2], 0, 0, 0);
        acc[nb][3] = __builtin_amdgcn_mfma_f32_16x16x32_bf16(a3, bf, acc[nb][3], 0, 0, 0);
      }
    }

    // Stage: C-layout row = mi*16 + quad*4 + reg, LDS col nn = n-(base-64)
#pragma unroll
    for (int nb = 0; nb < 2; nb++) {
      if (diag && nb == 0) continue;
#pragma unroll
      for (int mi = 0; mi < 4; mi++)
#pragma unroll
        for (int reg = 0; reg < 4; reg++)
          tile[mi * 16 + quad * 4 + reg][(nb << 6) + (w << 4) + ln] = acc[nb][mi][reg];
    }
    __syncthreads();

    // Aligned stores: row r, cols [c0, c0+64).  c = c0+lane, n = r-c,
    // nn = n-(base-64) = 64 + rr - lane  (in [1,127]); diag: c>r -> 0.
#pragma unroll
    for (int it = 0; it < 16; ++it) {
      const int rr = (it << 2) + w;
      float v = tile[rr][64 + rr - lane];
      if (diag && lane > rr) v = 0.f;
      obase[(size_t)(r0 + rr) * L + c0 + lane] = v;
    }
  }
}

extern "C" void kernel_launch(void* const* d_in, const int* in_sizes, int n_in,
                              void* d_out, int out_size, void* d_ws, size_t ws_size,
                              hipStream_t stream) {
  const float* q = (const float*)d_in[0];   // (2, 8, 2048, 64) fp32
  const float* e = (const float*)d_in[1];   // (8, 2048, 64) fp32
  float* out = (float*)d_out;               // (2, 8, 2048, 2048) fp32

  dim3 grid(16, NT * (NT + 1) / 2);   // (bh, lower-triangle pair) = (16, 528)
  skew_mfma<<<grid, 256, 0, stream>>>(q, e, out);
}